// Round 17
// baseline (145.418 us; speedup 1.0000x reference)
//
#include <hip/hip_runtime.h>

#define B_ 4
#define C_ 256
#define N_ 4096

typedef unsigned short u16;
typedef unsigned char u8;
typedef __bf16 bf16x8 __attribute__((ext_vector_type(8)));
typedef float f32x4 __attribute__((ext_vector_type(4)));
typedef float f32x16 __attribute__((ext_vector_type(16)));
typedef u16 u16x8 __attribute__((ext_vector_type(8)));
typedef u16 u16x4 __attribute__((ext_vector_type(4)));
typedef u8 u8x16 __attribute__((ext_vector_type(16)));
typedef int i32x4 __attribute__((ext_vector_type(4)));
typedef int i32x8 __attribute__((ext_vector_type(8)));

union BF8 { u16x8 u; bf16x8 b; };

__device__ __forceinline__ u16 f2bf(float f) {  // RNE
  unsigned int u = __float_as_uint(f);
  u += 0x7fffu + ((u >> 16) & 1u);
  return (u16)(u >> 16);
}
__device__ __forceinline__ u16 f2bf_fast(float f) {  // round-half-up
  return (u16)((__float_as_uint(f) + 0x8000u) >> 16);
}
__device__ __forceinline__ float bf2f(u16 u) {
  return __uint_as_float(((unsigned int)u) << 16);
}

__device__ __forceinline__ f32x16 mfma32(bf16x8 a, bf16x8 b, f32x16 c) {
  return __builtin_amdgcn_mfma_f32_32x32x16_bf16(a, b, c, 0, 0, 0);
}
// block-scaled fp8 MFMA, K=64, unit scales (e8m0 127 = 2^0): numerically
// identical to non-scaled fp8 but ~2.1x the MFMA rate.
__device__ __forceinline__ f32x16 mfma_sc64(i32x8 a, i32x8 b, f32x16 c) {
  return __builtin_amdgcn_mfma_scale_f32_32x32x64_f8f6f4(
      a, b, c, 0 /*A=fp8*/, 0 /*B=fp8*/, 0, 0x7f7f7f7f, 0, 0x7f7f7f7f);
}

// async global->LDS, 16B/lane, dest = wave-uniform base + lane*16
__device__ __forceinline__ void gl_lds16(const u8* g, u8* l) {
  __builtin_amdgcn_global_load_lds(
      (const __attribute__((address_space(1))) unsigned int*)g,
      (__attribute__((address_space(3))) unsigned int*)l, 16, 0, 0);
}

#define ROWMAP(r, half) (((r) & 3) + 8 * ((r) >> 2) + 4 * (half))

// sqrt((1/16)*log2e): folded into BOTH q and k -> softmax is bare exp2,
// and fp8 values sit in e4m3 normal range.
#define QK_SCALE 0.30028063f

// ---------------- weights fp32 -> bf16 fragment-order (once, tiny) ---------
__global__ __launch_bounds__(256) void k_prep(const float* __restrict__ wq,
                                              const float* __restrict__ wo,
                                              u16* __restrict__ Wqb,
                                              u16* __restrict__ Wob) {
  int i = blockIdx.x * 256 + threadIdx.x;  // 32768 = (384+128) gk * 64 lanes
  int lane = i & 63;
  int gk = i >> 6;  // g*16+ks: 0..383 -> Wqb, 384..511 -> Wob
  int l32 = lane & 31, half = lane >> 5;
  const float* src;
  u16* dst;
  if (gk < 384) {
    int o = (gk >> 4) * 32 + l32, k = (gk & 15) * 16 + half * 8;
    src = wq + (size_t)o * C_ + k;
    dst = Wqb + ((size_t)gk * 64 + lane) * 8;
  } else {
    int gk2 = gk - 384;
    int o = (gk2 >> 4) * 32 + l32, k = (gk2 & 15) * 16 + half * 8;
    src = wo + (size_t)o * C_ + k;
    dst = Wob + ((size_t)gk2 * 64 + lane) * 8;
  }
  f32x4 v0 = *(const f32x4*)src;
  f32x4 v1 = *(const f32x4*)(src + 4);
  u16x8 r = {f2bf(v0[0]), f2bf(v0[1]), f2bf(v0[2]), f2bf(v0[3]),
             f2bf(v1[0]), f2bf(v1[1]), f2bf(v1[2]), f2bf(v1[3])};
  *(u16x8*)dst = r;
}

// ---------------- QKV projection -> fp8 Q/K/V (proven 64-px form) ----------
__global__ __launch_bounds__(256, 2) void k_qkv(
    const u16* __restrict__ Wqb, const float* __restrict__ bias,
    const float* __restrict__ x, u8* __restrict__ Qt, u8* __restrict__ Kt,
    u8* __restrict__ Vn) {
  __shared__ u16 Xs[64 * 264];
  __shared__ u8 Sg[9216];  // SQ: [64 pix][136] or SV: [128 c][72]
  const int b = blockIdx.z, yb = blockIdx.y, n0 = blockIdx.x * 64;
  const int t = threadIdx.x, w = t >> 6, lane = t & 63;
  const int l32 = lane & 31, half = lane >> 5;

  // x tile [256 c][64 n] f32 -> Xs[n][c] bf16, 4x4 register micro-transpose
#pragma unroll
  for (int it = 0; it < 4; ++it) {
    int chunk = t + 256 * it;  // 0..1023
    int cq = chunk >> 4;       // 0..63: c-quad
    int nq = chunk & 15;       // 0..15: n-quad
    f32x4 r[4];
#pragma unroll
    for (int j = 0; j < 4; ++j)
      r[j] = *(const f32x4*)(x +
                             (((size_t)b * C_ + cq * 4 + j) * N_ + n0 + nq * 4));
#pragma unroll
    for (int i = 0; i < 4; ++i) {
      u16x4 col = {f2bf(r[0][i]), f2bf(r[1][i]), f2bf(r[2][i]), f2bf(r[3][i])};
      *(u16x4*)&Xs[(nq * 4 + i) * 264 + cq * 4] = col;
    }
  }
  __syncthreads();

  BF8 xf[2][16];
#pragma unroll
  for (int nt = 0; nt < 2; ++nt)
#pragma unroll
    for (int ks = 0; ks < 16; ++ks)
      xf[nt][ks].u =
          *(const u16x8*)&Xs[(nt * 32 + l32) * 264 + ks * 16 + half * 8];

#pragma unroll
  for (int mt = 0; mt < 3; ++mt) {
    const int omr = yb * 384 + mt * 128;  // 128-wide tile, uniform seg
    const int seg = omr >> 8;             // 0=Q 1=K 2=V
    const int ow = omr + w * 32;          // this wave's 32 outputs
    BF8 wf[16];
    const u16* wrow = Wqb + ((size_t)((omr >> 5) + w) * 16 * 64 + lane) * 8;
#pragma unroll
    for (int ks = 0; ks < 16; ++ks)
      wf[ks].u = *(const u16x8*)(wrow + (size_t)ks * 64 * 8);

    f32x16 a0, a1;
#pragma unroll
    for (int r = 0; r < 16; ++r) a0[r] = a1[r] = 0.f;

    if (seg < 2) {
      // A = wf (m=o), B = xf (n=pix): regs -> o = ow+ROWMAP, lane -> pix
#pragma unroll
      for (int ks = 0; ks < 16; ++ks) {
        a0 = mfma32(wf[ks].b, xf[0][ks].b, a0);
        a1 = mfma32(wf[ks].b, xf[1][ks].b, a1);
      }
#pragma unroll
      for (int nt = 0; nt < 2; ++nt) {
        const f32x16& a = nt ? a1 : a0;
#pragma unroll
        for (int g = 0; g < 4; ++g) {
          f32x4 bv = *(const f32x4*)&bias[ow + 8 * g + 4 * half];
          float v0 = (a[4 * g + 0] + bv[0]) * QK_SCALE;
          float v1 = (a[4 * g + 1] + bv[1]) * QK_SCALE;
          float v2 = (a[4 * g + 2] + bv[2]) * QK_SCALE;
          float v3 = (a[4 * g + 3] + bv[3]) * QK_SCALE;
          int pkw = __builtin_amdgcn_cvt_pk_fp8_f32(v0, v1, 0, false);
          pkw = __builtin_amdgcn_cvt_pk_fp8_f32(v2, v3, pkw, true);
          *(int*)&Sg[(nt * 32 + l32) * 136 + w * 32 + 8 * g + 4 * half] = pkw;
        }
      }
      __syncthreads();
      {  // full-128B-line stores: Qt/Kt[b][pix][ol..ol+128)
        u8* dst = ((seg == 0) ? Qt : Kt) + ((size_t)b * N_ + n0) * C_ +
                  (omr & 255);
        int row = t >> 2, cb = t & 3;
        u8x16 q0 = *(const u8x16*)&Sg[row * 136 + cb * 32];
        u8x16 q1 = *(const u8x16*)&Sg[row * 136 + cb * 32 + 16];
        u8* d = dst + (size_t)row * C_ + cb * 32;
        *(u8x16*)d = q0;
        *(u8x16*)(d + 16) = q1;
      }
      __syncthreads();
    } else {
      // A = xf (m=pix), B = wf (n=c): regs -> pix = ROWMAP, lane -> c
#pragma unroll
      for (int ks = 0; ks < 16; ++ks) {
        a0 = mfma32(xf[0][ks].b, wf[ks].b, a0);
        a1 = mfma32(xf[1][ks].b, wf[ks].b, a1);
      }
      const float bvv = bias[ow + l32];
#pragma unroll
      for (int nt = 0; nt < 2; ++nt) {
        const f32x16& a = nt ? a1 : a0;
#pragma unroll
        for (int g = 0; g < 4; ++g) {
          float v0 = a[4 * g + 0] + bvv, v1 = a[4 * g + 1] + bvv;
          float v2 = a[4 * g + 2] + bvv, v3 = a[4 * g + 3] + bvv;
          int pkw = __builtin_amdgcn_cvt_pk_fp8_f32(v0, v1, 0, false);
          pkw = __builtin_amdgcn_cvt_pk_fp8_f32(v2, v3, pkw, true);
          *(int*)&Sg[(w * 32 + l32) * 72 + nt * 32 + 8 * g + 4 * half] = pkw;
        }
      }
      __syncthreads();
      {  // Vn[b][c][n0..n0+64): 64B sectors
        u8* dst = Vn + ((size_t)b * C_ + (omr - 512)) * N_ + n0;
        int row = t >> 1, ch = t & 1;
        u8x16 q0 = *(const u8x16*)&Sg[row * 72 + ch * 32];
        u8x16 q1 = *(const u8x16*)&Sg[row * 72 + ch * 32 + 16];
        u8* d = dst + (size_t)row * N_ + ch * 32;
        *(u8x16*)d = q0;
        *(u8x16*)(d + 16) = q1;
      }
      __syncthreads();
    }
  }
}

// ---------------- elementwise combine: (U0..U3)/l + bias + residual --------
// U is bf16, 4 jq planes; Ml 8 planes. 2048 blocks x 256 thr x 8 elems.
__global__ __launch_bounds__(256) void k_out(
    const float* __restrict__ bias, const float* __restrict__ xres,
    float* __restrict__ outp, const u16* __restrict__ U,
    const float* __restrict__ Ml) {
  const int bid = blockIdx.x, tid = threadIdx.x;
  const int row = bid >> 1;  // b*C + c
  const int n = (bid & 1) * 2048 + tid * 8;
  const int b = row >> 8;
  const size_t idx = (size_t)row * N_ + n;
  const size_t TEN = (size_t)B_ * C_ * N_;
  const size_t BN = (size_t)B_ * N_;
  const size_t bn = (size_t)b * N_ + n;
  u16x8 u0 = *(const u16x8*)&U[idx];
  u16x8 u1 = *(const u16x8*)&U[TEN + idx];
  u16x8 u2 = *(const u16x8*)&U[2 * TEN + idx];
  u16x8 u3 = *(const u16x8*)&U[3 * TEN + idx];
  f32x4 xr0 = *(const f32x4*)&xres[idx];
  f32x4 xr1 = *(const f32x4*)&xres[idx + 4];
  f32x4 la0 = {0.f, 0.f, 0.f, 0.f}, la1 = {0.f, 0.f, 0.f, 0.f};
#pragma unroll
  for (int p = 0; p < 8; ++p) {
    la0 += *(const f32x4*)&Ml[p * BN + bn];
    la1 += *(const f32x4*)&Ml[p * BN + bn + 4];
  }
  const float bc = bias[row & 255];
  f32x4 o0, o1;
#pragma unroll
  for (int i = 0; i < 4; ++i) {
    o0[i] = (bf2f(u0[i]) + bf2f(u1[i]) + bf2f(u2[i]) + bf2f(u3[i])) / la0[i] +
            bc + xr0[i];
    o1[i] = (bf2f(u0[4 + i]) + bf2f(u1[4 + i]) + bf2f(u2[4 + i]) +
             bf2f(u3[4 + i])) / la1[i] + bc + xr1[i];
  }
  *(f32x4*)&outp[idx] = o0;
  *(f32x4*)&outp[idx + 4] = o1;
}

// ---------------- flash attention + fused out-projection (bf16 U planes).
// 2 BLOCKS/CU retry with CORRECT register bound: launch_bounds(512, 2).
// CUDA semantics (2nd arg = min BLOCKS/CU, confirmed by R13/R14: (*,4)
// -> VGPR cap 64 both times = 2048/(4*8waves/4simd)): (512,2) -> 16
// waves/CU = 4/SIMD -> cap 128 >= ~96 live regs -> no spill.
// LDS 81920 B x 2 = 163840 = full 160 KiB pool: K dbuf @0 (2x16K),
// V dbuf @32768 (2x16K), P dbuf @65536 (2x8K).
// grid 512 = 4b x 4jq x 32 q-tiles of 128 px, 16 iters/block.
// Schedule per iter t: kstage K(t+1)->slot (t+1)&1; vmcnt(4) [FIFO: retires
// K(t) and older; V(t-1) already retired previous iter]; QK(t); PV(t-1)
// [V slot (t-1)&1, P parity (t-1)&1]; softpub P(t)->parity t&1;
// lgkmcnt(0)+barrier [P visibility + KV WAR]; vstage V(t+1)->slot (t+1)&1
// (slot PV just vacated; all waves passed the barrier after their reads).
__global__ __launch_bounds__(512, 2) void k_attn(
    const u8* __restrict__ Qt, const u8* __restrict__ Kt,
    const u8* __restrict__ Vn, const u16* __restrict__ Wob,
    u16* __restrict__ U, float* __restrict__ Ml) {
  __shared__ u8 raw[81920];
  const int id = blockIdx.x;
  const int b = (id >> 1) & 3;
  const int jq = (id & 1) | (((id >> 3) & 1) << 1);
  const int i0 = (id >> 4) * 128;
  const int t = threadIdx.x, w = t >> 6, lane = t & 63;
  const int l32 = lane & 31, half = lane >> 5;
  const int mh = w >> 1, hh = w & 1;

  // Q fragment: pixel row = i0 + mh*32 + l32; lane holds k = half*32+[0,32)
  i32x8 qf8[4];
  {
    const u8* qrow =
        Qt + ((size_t)b * N_ + i0 + mh * 32 + l32) * C_ + half * 32;
#pragma unroll
    for (int kb = 0; kb < 4; ++kb) {
      i32x4 r0 = *(const i32x4*)(qrow + kb * 64);
      i32x4 r1 = *(const i32x4*)(qrow + kb * 64 + 16);
      qf8[kb] = __builtin_shufflevector(r0, r1, 0, 1, 2, 3, 4, 5, 6, 7);
    }
  }
  f32x16 o[4];  // channels hh*128+ct*32+ROWMAP(r,half), pixel mh*32+l32
#pragma unroll
  for (int ct = 0; ct < 4; ++ct)
#pragma unroll
    for (int r = 0; r < 16; ++r) o[ct][r] = 0.f;
  float l_i = 0.f;

  const u8* kbase = Kt + (size_t)b * N_ * C_;
  const u8* vbase = Vn + (size_t)b * (size_t)C_ * N_;
  const int jbeg = jq * (N_ / 4);

  const int kR = lane >> 4, kG = lane & 15;  // K: 4 rows/wave/call
  const int vR = lane >> 2, vG = lane & 3;   // V: 16 rows/wave/call

  // Hoisted per-lane staging pointers; swizzle keys tile-invariant.
  const u8* kpr = kbase + (size_t)(jbeg + w * 4 + kR) * C_;
  const u8* vpr = vbase + (size_t)(w * 16 + vR) * N_ + jbeg;
  int ksw[2];
#pragma unroll
  for (int it = 0; it < 2; ++it)
    ksw[it] = it * 32 * C_ + ((kG ^ ((w * 4 + kR) & 15)) << 4);
  const int vkey = ((vR >> 1) ^ (w * 2 + (vR >> 3))) & 3;
  int vsw[2];
#pragma unroll
  for (int it = 0; it < 2; ++it)
    vsw[it] = it * 128 * N_ + ((vG ^ vkey) << 4);

  auto kstage = [&](int kb) {  // one 64-j K tile into byte offset kb; advance
    gl_lds16(kpr + ksw[0], raw + kb + w * 1024);
    gl_lds16(kpr + ksw[1], raw + kb + 8192 + w * 1024);
    kpr += 64 * C_;
  };
  auto vstage = [&](int vs) {  // one 64-j V tile into V region offset vs
    gl_lds16(vpr + vsw[0], raw + 32768 + vs + w * 1024);
    gl_lds16(vpr + vsw[1], raw + 32768 + vs + 8192 + w * 1024);
    vpr += 64;
  };

  const int jrow = hh * 32 + l32;  // K row whose S this wave computes
  const int rx = (jrow & 15) << 4;
  const int pm = ((l32 >> 1) ^ (l32 >> 3)) & 3;  // P/V granule swizzle key
  u8* Prow = raw + 65536 + mh * 2048 + l32 * 64;  // + parity offset

  auto do_qk = [&](int kbr) {
    f32x16 s;
#pragma unroll
    for (int r = 0; r < 16; ++r) s[r] = 0.f;
    const u8* krowp = raw + kbr + jrow * 256;
    __builtin_amdgcn_s_setprio(1);
#pragma unroll
    for (int kb = 0; kb < 4; ++kb) {
      const int base = kb * 64 + half * 32;
      i32x4 r0 = *(const i32x4*)(krowp + (base ^ rx));
      i32x4 r1 = *(const i32x4*)(krowp + ((base + 16) ^ rx));
      i32x8 kf8 = __builtin_shufflevector(r0, r1, 0, 1, 2, 3, 4, 5, 6, 7);
      s = mfma_sc64(kf8, qf8[kb], s);
    }
    __builtin_amdgcn_s_setprio(0);
    return s;
  };
  auto do_softpub = [&](const f32x16& s, int pwr) {
    float tile_sum = 0.f;
#pragma unroll
    for (int g = 0; g < 4; ++g) {
      float p0 = __builtin_amdgcn_exp2f(s[4 * g + 0]);
      float p1 = __builtin_amdgcn_exp2f(s[4 * g + 1]);
      float p2 = __builtin_amdgcn_exp2f(s[4 * g + 2]);
      float p3 = __builtin_amdgcn_exp2f(s[4 * g + 3]);
      tile_sum += (p0 + p1) + (p2 + p3);
      int w0 = __builtin_amdgcn_cvt_pk_fp8_f32(p0, p1, 0, false);
      int pkw = __builtin_amdgcn_cvt_pk_fp8_f32(p2, p3, w0, true);
      int adr = (((2 * hh + (g >> 1)) ^ pm) << 4) + (2 * (g & 1) + half) * 4;
      *(int*)(Prow + pwr + adr) = pkw;
    }
    tile_sum += __shfl_xor(tile_sum, 32);
    l_i += tile_sum;
  };
  auto do_pv = [&](int prd, int vrd) {
    const u8* Pl = Prow + prd;
    i32x4 p0 = *(const i32x4*)(Pl + (((2 * half + 0) ^ pm) << 4));
    i32x4 p1 = *(const i32x4*)(Pl + (((2 * half + 1) ^ pm) << 4));
    i32x8 pf = __builtin_shufflevector(p0, p1, 0, 1, 2, 3, 4, 5, 6, 7);
    const u8* vbp = raw + 32768 + vrd + (hh * 128 + l32) * 64;
    __builtin_amdgcn_s_setprio(1);
#pragma unroll
    for (int ct = 0; ct < 4; ++ct) {
      const u8* vrowp = vbp + ct * 32 * 64;
      i32x4 v0 = *(const i32x4*)(vrowp + (((2 * half + 0) ^ pm) << 4));
      i32x4 v1 = *(const i32x4*)(vrowp + (((2 * half + 1) ^ pm) << 4));
      i32x8 vf = __builtin_shufflevector(v0, v1, 0, 1, 2, 3, 4, 5, 6, 7);
      o[ct] = mfma_sc64(vf, pf, o[ct]);
    }
    __builtin_amdgcn_s_setprio(0);
  };

  // prologue: K(0)->slot0, V(0)->slot0; full drain once.
  kstage(0);
  vstage(0);
  __syncthreads();

  // iter 0: K(1)->slot1; QK(0); P(0)->parity0; barrier; V(1)->slot1.
  kstage(16384);
  {
    f32x16 s = do_qk(0);
    do_softpub(s, 0);
  }
  __builtin_amdgcn_sched_barrier(0);
  asm volatile("s_waitcnt lgkmcnt(0)\n\ts_barrier" ::: "memory");
  __builtin_amdgcn_sched_barrier(0);
  vstage(16384);

  // steady state t=1..15: kr=t&1, vr=(t-1)&1, prd=((t-1)&1)*8192.
  int kr = 1, vr = 0, prd = 0;
  for (int it = 1; it < 16; ++it) {
    if (it == 15) kpr -= (size_t)(N_ / 4) * C_;  // K(16) dummy wrap
    kstage((kr ^ 1) * 16384);                    // K(t+1) -> slot (t+1)&1
    __builtin_amdgcn_sched_barrier(0);
    asm volatile("s_waitcnt vmcnt(4)" ::: "memory");  // retires K(t) & older
    __builtin_amdgcn_sched_barrier(0);
    f32x16 s = do_qk(kr * 16384);
    do_pv(prd, vr * 16384);
    do_softpub(s, prd ^ 8192);
    __builtin_amdgcn_sched_barrier(0);
    asm volatile("s_waitcnt lgkmcnt(0)\n\ts_barrier" ::: "memory");
    __builtin_amdgcn_sched_barrier(0);
    if (it == 15) vpr -= N_ / 4;                 // V(16) dummy wrap
    vstage(vr * 16384);  // V(t+1) -> slot (t+1)&1 == vr (just vacated by PV)
    kr ^= 1;
    vr ^= 1;
    prd ^= 8192;
  }
  // drain PV(15): prd=8192 (parity 1), V(15) slot 1 (vr==1 now).
  // vmcnt(4): outstanding <= {V(15)2,K(16)2,V(16)2}; retires oldest 2 = V(15).
  __builtin_amdgcn_sched_barrier(0);
  asm volatile("s_waitcnt vmcnt(4)" ::: "memory");
  __builtin_amdgcn_sched_barrier(0);
  do_pv(prd, vr * 16384);

  // ---- write l partials; stage O^T (bf16) into M for the out-proj GEMM
  float* ml = Ml + ((size_t)(jq * 2 + hh) * B_ + b) * N_;
  if (lane < 32) ml[i0 + mh * 32 + l32] = l_i;
  __syncthreads();  // full drain: PV reads + dummy loads land before raw reuse

  u16* M = (u16*)raw;  // [128][264] = 67584 B <= 81920
#pragma unroll
  for (int ct = 0; ct < 4; ++ct)
#pragma unroll
    for (int g = 0; g < 4; ++g) {
      u16x4 pkv = {f2bf_fast(o[ct][4 * g + 0]), f2bf_fast(o[ct][4 * g + 1]),
                   f2bf_fast(o[ct][4 * g + 2]), f2bf_fast(o[ct][4 * g + 3])};
      *(u16x4*)&M[(mh * 32 + l32) * 264 + hh * 128 + ct * 32 + 8 * g +
                  4 * half] = pkv;
    }
  __syncthreads();

  // ---- fused out-proj: U_jq[oc][px] = sum_c Wob[oc][c] * M[px][c]; bf16 out.
  {
    BF8 wf[16];
    const u16* wrow = Wob + ((size_t)w * 16 * 64 + lane) * 8;
#pragma unroll
    for (int ks = 0; ks < 16; ++ks)
      wf[ks].u = *(const u16x8*)(wrow + (size_t)ks * 64 * 8);
    u16* up = U + (((size_t)jq * B_ + b) * C_ + w * 32) * (size_t)N_ + i0;
#pragma unroll
    for (int pxt = 0; pxt < 4; ++pxt) {
      BF8 xf[16];
#pragma unroll
      for (int ks = 0; ks < 16; ++ks)
        xf[ks].u =
            *(const u16x8*)&M[(pxt * 32 + l32) * 264 + ks * 16 + half * 8];
      f32x16 a;
#pragma unroll
      for (int r = 0; r < 16; ++r) a[r] = 0.f;
#pragma unroll
      for (int ks = 0; ks < 16; ++ks) a = mfma32(wf[ks].b, xf[ks].b, a);
#pragma unroll
      for (int r = 0; r < 16; ++r)
        up[(size_t)ROWMAP(r, half) * N_ + pxt * 32 + l32] = f2bf_fast(a[r]);
    }
  }
}

extern "C" void kernel_launch(void* const* d_in, const int* in_sizes, int n_in,
                              void* d_out, int out_size, void* d_ws,
                              size_t ws_size, hipStream_t stream) {
  (void)in_sizes; (void)n_in; (void)out_size; (void)ws_size;
  const float* x = (const float*)d_in[0];
  const float* w_qkv = (const float*)d_in[1];
  const float* b_qkv = (const float*)d_in[2];
  const float* w_out = (const float*)d_in[3];
  const float* b_out = (const float*)d_in[4];
  float* outp = (float*)d_out;

  const size_t TENS = (size_t)B_ * N_ * C_;  // 4M elems
  u8* Qt = (u8*)d_ws;           // [B][N][C] fp8 (scaled)      4 MB
  u8* Kt = Qt + TENS;           // [B][N][C] fp8 (scaled)      4 MB
  u8* Vn = Kt + TENS;           // [B][C][N] fp8               4 MB
  u16* U = (u16*)(Vn + TENS);                   // [4][B][C][N] bf16 33.6 MB
  float* Ml = (float*)(U + 4 * TENS);           // [8][B][N]  512 KB
  u16* Wqb = (u16*)(Ml + 8 * (size_t)B_ * N_);  // [3C][C]    384 KB
  u16* Wob = Wqb + 3 * C_ * C_;                 // [C][C]     128 KB

  k_prep<<<dim3(128), 256, 0, stream>>>(w_qkv, w_out, Wqb, Wob);
  k_qkv<<<dim3(64, 2, 4), 256, 0, stream>>>(Wqb, b_qkv, x, Qt, Kt, Vn);
  k_attn<<<dim3(512), 512, 0, stream>>>(Qt, Kt, Vn, Wob, U, Ml);
  k_out<<<dim3(2048), 256, 0, stream>>>(b_out, x, outp, U, Ml);
}

// Round 18
// 135.823 us; speedup vs baseline: 1.0706x; 1.0706x over previous
//
#include <hip/hip_runtime.h>

#define B_ 4
#define C_ 256
#define N_ 4096

typedef unsigned short u16;
typedef unsigned char u8;
typedef __bf16 bf16x8 __attribute__((ext_vector_type(8)));
typedef float f32x4 __attribute__((ext_vector_type(4)));
typedef float f32x16 __attribute__((ext_vector_type(16)));
typedef u16 u16x8 __attribute__((ext_vector_type(8)));
typedef u16 u16x4 __attribute__((ext_vector_type(4)));
typedef u8 u8x16 __attribute__((ext_vector_type(16)));
typedef int i32x4 __attribute__((ext_vector_type(4)));
typedef int i32x8 __attribute__((ext_vector_type(8)));

union BF8 { u16x8 u; bf16x8 b; };

__device__ __forceinline__ u16 f2bf(float f) {  // RNE
  unsigned int u = __float_as_uint(f);
  u += 0x7fffu + ((u >> 16) & 1u);
  return (u16)(u >> 16);
}
__device__ __forceinline__ u16 f2bf_fast(float f) {  // round-half-up
  return (u16)((__float_as_uint(f) + 0x8000u) >> 16);
}
__device__ __forceinline__ float bf2f(u16 u) {
  return __uint_as_float(((unsigned int)u) << 16);
}

__device__ __forceinline__ f32x16 mfma32(bf16x8 a, bf16x8 b, f32x16 c) {
  return __builtin_amdgcn_mfma_f32_32x32x16_bf16(a, b, c, 0, 0, 0);
}
// block-scaled fp8 MFMA, K=64, unit scales (e8m0 127 = 2^0): numerically
// identical to non-scaled fp8 but ~2.1x the MFMA rate.
__device__ __forceinline__ f32x16 mfma_sc64(i32x8 a, i32x8 b, f32x16 c) {
  return __builtin_amdgcn_mfma_scale_f32_32x32x64_f8f6f4(
      a, b, c, 0 /*A=fp8*/, 0 /*B=fp8*/, 0, 0x7f7f7f7f, 0, 0x7f7f7f7f);
}

// async global->LDS, 16B/lane, dest = wave-uniform base + lane*16
__device__ __forceinline__ void gl_lds16(const u8* g, u8* l) {
  __builtin_amdgcn_global_load_lds(
      (const __attribute__((address_space(1))) unsigned int*)g,
      (__attribute__((address_space(3))) unsigned int*)l, 16, 0, 0);
}

#define ROWMAP(r, half) (((r) & 3) + 8 * ((r) >> 2) + 4 * (half))

// sqrt((1/16)*log2e): folded into BOTH q and k -> softmax is bare exp2,
// and fp8 values sit in e4m3 normal range.
#define QK_SCALE 0.30028063f

// ---------------- weights fp32 -> bf16 fragment-order (once, tiny) ---------
__global__ __launch_bounds__(256) void k_prep(const float* __restrict__ wq,
                                              const float* __restrict__ wo,
                                              u16* __restrict__ Wqb,
                                              u16* __restrict__ Wob) {
  int i = blockIdx.x * 256 + threadIdx.x;  // 32768 = (384+128) gk * 64 lanes
  int lane = i & 63;
  int gk = i >> 6;  // g*16+ks: 0..383 -> Wqb, 384..511 -> Wob
  int l32 = lane & 31, half = lane >> 5;
  const float* src;
  u16* dst;
  if (gk < 384) {
    int o = (gk >> 4) * 32 + l32, k = (gk & 15) * 16 + half * 8;
    src = wq + (size_t)o * C_ + k;
    dst = Wqb + ((size_t)gk * 64 + lane) * 8;
  } else {
    int gk2 = gk - 384;
    int o = (gk2 >> 4) * 32 + l32, k = (gk2 & 15) * 16 + half * 8;
    src = wo + (size_t)o * C_ + k;
    dst = Wob + ((size_t)gk2 * 64 + lane) * 8;
  }
  f32x4 v0 = *(const f32x4*)src;
  f32x4 v1 = *(const f32x4*)(src + 4);
  u16x8 r = {f2bf(v0[0]), f2bf(v0[1]), f2bf(v0[2]), f2bf(v0[3]),
             f2bf(v1[0]), f2bf(v1[1]), f2bf(v1[2]), f2bf(v1[3])};
  *(u16x8*)dst = r;
}

// ---------------- QKV projection -> fp8 Q/K/V (proven 64-px form) ----------
__global__ __launch_bounds__(256, 2) void k_qkv(
    const u16* __restrict__ Wqb, const float* __restrict__ bias,
    const float* __restrict__ x, u8* __restrict__ Qt, u8* __restrict__ Kt,
    u8* __restrict__ Vn) {
  __shared__ u16 Xs[64 * 264];
  __shared__ u8 Sg[9216];  // SQ: [64 pix][136] or SV: [128 c][72]
  const int b = blockIdx.z, yb = blockIdx.y, n0 = blockIdx.x * 64;
  const int t = threadIdx.x, w = t >> 6, lane = t & 63;
  const int l32 = lane & 31, half = lane >> 5;

  // x tile [256 c][64 n] f32 -> Xs[n][c] bf16, 4x4 register micro-transpose
#pragma unroll
  for (int it = 0; it < 4; ++it) {
    int chunk = t + 256 * it;  // 0..1023
    int cq = chunk >> 4;       // 0..63: c-quad
    int nq = chunk & 15;       // 0..15: n-quad
    f32x4 r[4];
#pragma unroll
    for (int j = 0; j < 4; ++j)
      r[j] = *(const f32x4*)(x +
                             (((size_t)b * C_ + cq * 4 + j) * N_ + n0 + nq * 4));
#pragma unroll
    for (int i = 0; i < 4; ++i) {
      u16x4 col = {f2bf(r[0][i]), f2bf(r[1][i]), f2bf(r[2][i]), f2bf(r[3][i])};
      *(u16x4*)&Xs[(nq * 4 + i) * 264 + cq * 4] = col;
    }
  }
  __syncthreads();

  BF8 xf[2][16];
#pragma unroll
  for (int nt = 0; nt < 2; ++nt)
#pragma unroll
    for (int ks = 0; ks < 16; ++ks)
      xf[nt][ks].u =
          *(const u16x8*)&Xs[(nt * 32 + l32) * 264 + ks * 16 + half * 8];

#pragma unroll
  for (int mt = 0; mt < 3; ++mt) {
    const int omr = yb * 384 + mt * 128;  // 128-wide tile, uniform seg
    const int seg = omr >> 8;             // 0=Q 1=K 2=V
    const int ow = omr + w * 32;          // this wave's 32 outputs
    BF8 wf[16];
    const u16* wrow = Wqb + ((size_t)((omr >> 5) + w) * 16 * 64 + lane) * 8;
#pragma unroll
    for (int ks = 0; ks < 16; ++ks)
      wf[ks].u = *(const u16x8*)(wrow + (size_t)ks * 64 * 8);

    f32x16 a0, a1;
#pragma unroll
    for (int r = 0; r < 16; ++r) a0[r] = a1[r] = 0.f;

    if (seg < 2) {
      // A = wf (m=o), B = xf (n=pix): regs -> o = ow+ROWMAP, lane -> pix
#pragma unroll
      for (int ks = 0; ks < 16; ++ks) {
        a0 = mfma32(wf[ks].b, xf[0][ks].b, a0);
        a1 = mfma32(wf[ks].b, xf[1][ks].b, a1);
      }
#pragma unroll
      for (int nt = 0; nt < 2; ++nt) {
        const f32x16& a = nt ? a1 : a0;
#pragma unroll
        for (int g = 0; g < 4; ++g) {
          f32x4 bv = *(const f32x4*)&bias[ow + 8 * g + 4 * half];
          float v0 = (a[4 * g + 0] + bv[0]) * QK_SCALE;
          float v1 = (a[4 * g + 1] + bv[1]) * QK_SCALE;
          float v2 = (a[4 * g + 2] + bv[2]) * QK_SCALE;
          float v3 = (a[4 * g + 3] + bv[3]) * QK_SCALE;
          int pkw = __builtin_amdgcn_cvt_pk_fp8_f32(v0, v1, 0, false);
          pkw = __builtin_amdgcn_cvt_pk_fp8_f32(v2, v3, pkw, true);
          *(int*)&Sg[(nt * 32 + l32) * 136 + w * 32 + 8 * g + 4 * half] = pkw;
        }
      }
      __syncthreads();
      {  // full-128B-line stores: Qt/Kt[b][pix][ol..ol+128)
        u8* dst = ((seg == 0) ? Qt : Kt) + ((size_t)b * N_ + n0) * C_ +
                  (omr & 255);
        int row = t >> 2, cb = t & 3;
        u8x16 q0 = *(const u8x16*)&Sg[row * 136 + cb * 32];
        u8x16 q1 = *(const u8x16*)&Sg[row * 136 + cb * 32 + 16];
        u8* d = dst + (size_t)row * C_ + cb * 32;
        *(u8x16*)d = q0;
        *(u8x16*)(d + 16) = q1;
      }
      __syncthreads();
    } else {
      // A = xf (m=pix), B = wf (n=c): regs -> pix = ROWMAP, lane -> c
#pragma unroll
      for (int ks = 0; ks < 16; ++ks) {
        a0 = mfma32(xf[0][ks].b, wf[ks].b, a0);
        a1 = mfma32(xf[1][ks].b, wf[ks].b, a1);
      }
      const float bvv = bias[ow + l32];
#pragma unroll
      for (int nt = 0; nt < 2; ++nt) {
        const f32x16& a = nt ? a1 : a0;
#pragma unroll
        for (int g = 0; g < 4; ++g) {
          float v0 = a[4 * g + 0] + bvv, v1 = a[4 * g + 1] + bvv;
          float v2 = a[4 * g + 2] + bvv, v3 = a[4 * g + 3] + bvv;
          int pkw = __builtin_amdgcn_cvt_pk_fp8_f32(v0, v1, 0, false);
          pkw = __builtin_amdgcn_cvt_pk_fp8_f32(v2, v3, pkw, true);
          *(int*)&Sg[(w * 32 + l32) * 72 + nt * 32 + 8 * g + 4 * half] = pkw;
        }
      }
      __syncthreads();
      {  // Vn[b][c][n0..n0+64): 64B sectors
        u8* dst = Vn + ((size_t)b * C_ + (omr - 512)) * N_ + n0;
        int row = t >> 1, ch = t & 1;
        u8x16 q0 = *(const u8x16*)&Sg[row * 72 + ch * 32];
        u8x16 q1 = *(const u8x16*)&Sg[row * 72 + ch * 32 + 16];
        u8* d = dst + (size_t)row * N_ + ch * 32;
        *(u8x16*)d = q0;
        *(u8x16*)(d + 16) = q1;
      }
      __syncthreads();
    }
  }
}

// ---------------- elementwise combine: (U0+U1)/l + bias + residual ----------
// U is bf16. 2048 blocks x 256 thr x 8 elems.
__global__ __launch_bounds__(256) void k_out(
    const float* __restrict__ bias, const float* __restrict__ xres,
    float* __restrict__ outp, const u16* __restrict__ U,
    const float* __restrict__ Ml) {
  const int bid = blockIdx.x, tid = threadIdx.x;
  const int row = bid >> 1;  // b*C + c
  const int n = (bid & 1) * 2048 + tid * 8;
  const int b = row >> 8;
  const size_t idx = (size_t)row * N_ + n;
  const size_t TEN = (size_t)B_ * C_ * N_;
  const size_t BN = (size_t)B_ * N_;
  const size_t bn = (size_t)b * N_ + n;
  u16x8 u0 = *(const u16x8*)&U[idx];
  u16x8 u1 = *(const u16x8*)&U[TEN + idx];
  f32x4 xr0 = *(const f32x4*)&xres[idx];
  f32x4 xr1 = *(const f32x4*)&xres[idx + 4];
  const float bc = bias[row & 255];
  f32x4 o0, o1;
#pragma unroll
  for (int i = 0; i < 4; ++i) {
    float li = Ml[bn + i] + Ml[BN + bn + i] + Ml[2 * BN + bn + i] +
               Ml[3 * BN + bn + i];
    o0[i] = (bf2f(u0[i]) + bf2f(u1[i])) / li + bc + xr0[i];
    float lj = Ml[bn + 4 + i] + Ml[BN + bn + 4 + i] +
               Ml[2 * BN + bn + 4 + i] + Ml[3 * BN + bn + 4 + i];
    o1[i] = (bf2f(u0[4 + i]) + bf2f(u1[4 + i])) / lj + bc + xr1[i];
  }
  *(f32x4*)&outp[idx] = o0;
  *(f32x4*)&outp[idx + 4] = o1;
}

// ---------------- flash attention + fused out-projection (bf16 U planes).
// SESSION-BEST CONFIG (R16, 136.0 us total): P-lagged pipeline, 8 waves /
// 128 px, grid 256 = 4b x 2jh x 32 q-tiles. 2-tile-deep prefetch (T4):
// K tri-buf @0 (3x16K), V tri-buf @49152 (3x16K), P dbuf @98304 (2x8K);
// per-iter barrier is counted: s_waitcnt vmcnt(4) lgkmcnt(0); s_barrier --
// this iter's 4 loads stay in flight across the barrier.
// Slot math: K(j)/V(j) live in slot j%3. Iter t: issue K(t+2),V(t+1);
// QK(t) reads slot t%3; PV(t-1) reads V slot (t-1)%3, P parity (t-1)&1.
// RAW: reads at t were issued at t-2, retired by end-of-(t-1) vmcnt(4).
// WAR: slot (t+2)%3 held K(t-1), whose readers passed barrier(t-1->t).
// NOTE occupancy levers are closed (measured): o[4] acc = 64 VGPR pins
// ~92 live regs (cap<92 spills: R13/R14 VGPR=64, FETCH 80-184 MB);
// LDS cannot halve (2x81920 denied residency: R17 occupancy ~20%).
__global__ __launch_bounds__(512, 1) void k_attn(
    const u8* __restrict__ Qt, const u8* __restrict__ Kt,
    const u8* __restrict__ Vn, const u16* __restrict__ Wob,
    u16* __restrict__ U, float* __restrict__ Ml) {
  __shared__ u8 raw[114688];
  const int id = blockIdx.x;
  const int xcd = id & 7;
  const int b = xcd >> 1;
  const int jh = xcd & 1;
  const int i0 = (id >> 3) * 128;
  const int t = threadIdx.x, w = t >> 6, lane = t & 63;
  const int l32 = lane & 31, half = lane >> 5;
  const int mh = w >> 1, hh = w & 1;

  // Q fragment: pixel row = i0 + mh*32 + l32; lane holds k = half*32+[0,32)
  i32x8 qf8[4];
  {
    const u8* qrow =
        Qt + ((size_t)b * N_ + i0 + mh * 32 + l32) * C_ + half * 32;
#pragma unroll
    for (int kb = 0; kb < 4; ++kb) {
      i32x4 r0 = *(const i32x4*)(qrow + kb * 64);
      i32x4 r1 = *(const i32x4*)(qrow + kb * 64 + 16);
      qf8[kb] = __builtin_shufflevector(r0, r1, 0, 1, 2, 3, 4, 5, 6, 7);
    }
  }
  f32x16 o[4];  // channels hh*128+ct*32+ROWMAP(r,half), pixel mh*32+l32
#pragma unroll
  for (int ct = 0; ct < 4; ++ct)
#pragma unroll
    for (int r = 0; r < 16; ++r) o[ct][r] = 0.f;
  float l_i = 0.f;

  const u8* kbase = Kt + (size_t)b * N_ * C_;
  const u8* vbase = Vn + (size_t)b * (size_t)C_ * N_;
  const int jbeg = jh * (N_ / 2);

  const int kR = lane >> 4, kG = lane & 15;  // K: 4 rows/wave/call
  const int vR = lane >> 2, vG = lane & 3;   // V: 16 rows/wave/call

  // Hoisted per-lane staging pointers; swizzle keys tile-invariant.
  const u8* kpr = kbase + (size_t)(jbeg + w * 4 + kR) * C_;
  const u8* vpr = vbase + (size_t)(w * 16 + vR) * N_ + jbeg;
  int ksw[2];
#pragma unroll
  for (int it = 0; it < 2; ++it)
    ksw[it] = it * 32 * C_ + ((kG ^ ((w * 4 + kR) & 15)) << 4);
  const int vkey = ((vR >> 1) ^ (w * 2 + (vR >> 3))) & 3;
  int vsw[2];
#pragma unroll
  for (int it = 0; it < 2; ++it)
    vsw[it] = it * 128 * N_ + ((vG ^ vkey) << 4);

  auto kstage = [&](int kb) {  // one 64-j K tile into byte offset kb; advance
    gl_lds16(kpr + ksw[0], raw + kb + w * 1024);
    gl_lds16(kpr + ksw[1], raw + kb + 8192 + w * 1024);
    kpr += 64 * C_;
  };
  auto vstage = [&](int vs) {  // one 64-j V tile into V region offset vs
    gl_lds16(vpr + vsw[0], raw + 49152 + vs + w * 1024);
    gl_lds16(vpr + vsw[1], raw + 49152 + vs + 8192 + w * 1024);
    vpr += 64;
  };

  const int jrow = hh * 32 + l32;  // K row whose S this wave computes
  const int rx = (jrow & 15) << 4;
  const int pm = ((l32 >> 1) ^ (l32 >> 3)) & 3;  // P/V granule swizzle key
  u8* Prow = raw + 98304 + mh * 2048 + l32 * 64;  // + parity offset

  auto do_qk = [&](int kbr) {
    f32x16 s;
#pragma unroll
    for (int r = 0; r < 16; ++r) s[r] = 0.f;
    const u8* krowp = raw + kbr + jrow * 256;
    __builtin_amdgcn_s_setprio(1);
#pragma unroll
    for (int kb = 0; kb < 4; ++kb) {
      const int base = kb * 64 + half * 32;
      i32x4 r0 = *(const i32x4*)(krowp + (base ^ rx));
      i32x4 r1 = *(const i32x4*)(krowp + ((base + 16) ^ rx));
      i32x8 kf8 = __builtin_shufflevector(r0, r1, 0, 1, 2, 3, 4, 5, 6, 7);
      s = mfma_sc64(kf8, qf8[kb], s);
    }
    __builtin_amdgcn_s_setprio(0);
    return s;
  };
  auto do_softpub = [&](const f32x16& s, int pwr) {
    float tile_sum = 0.f;
#pragma unroll
    for (int g = 0; g < 4; ++g) {
      float p0 = __builtin_amdgcn_exp2f(s[4 * g + 0]);
      float p1 = __builtin_amdgcn_exp2f(s[4 * g + 1]);
      float p2 = __builtin_amdgcn_exp2f(s[4 * g + 2]);
      float p3 = __builtin_amdgcn_exp2f(s[4 * g + 3]);
      tile_sum += (p0 + p1) + (p2 + p3);
      int w0 = __builtin_amdgcn_cvt_pk_fp8_f32(p0, p1, 0, false);
      int pkw = __builtin_amdgcn_cvt_pk_fp8_f32(p2, p3, w0, true);
      int adr = (((2 * hh + (g >> 1)) ^ pm) << 4) + (2 * (g & 1) + half) * 4;
      *(int*)(Prow + pwr + adr) = pkw;
    }
    tile_sum += __shfl_xor(tile_sum, 32);
    l_i += tile_sum;
  };
  auto do_pv = [&](int prd, int vrd) {
    const u8* Pl = Prow + prd;
    i32x4 p0 = *(const i32x4*)(Pl + (((2 * half + 0) ^ pm) << 4));
    i32x4 p1 = *(const i32x4*)(Pl + (((2 * half + 1) ^ pm) << 4));
    i32x8 pf = __builtin_shufflevector(p0, p1, 0, 1, 2, 3, 4, 5, 6, 7);
    const u8* vbp = raw + 49152 + vrd + (hh * 128 + l32) * 64;
    __builtin_amdgcn_s_setprio(1);
#pragma unroll
    for (int ct = 0; ct < 4; ++ct) {
      const u8* vrowp = vbp + ct * 32 * 64;
      i32x4 v0 = *(const i32x4*)(vrowp + (((2 * half + 0) ^ pm) << 4));
      i32x4 v1 = *(const i32x4*)(vrowp + (((2 * half + 1) ^ pm) << 4));
      i32x8 vf = __builtin_shufflevector(v0, v1, 0, 1, 2, 3, 4, 5, 6, 7);
      o[ct] = mfma_sc64(vf, pf, o[ct]);
    }
    __builtin_amdgcn_s_setprio(0);
  };

  // prologue: K(0),K(1),V(0); full drain once.
  kstage(0);        // K(0) -> slot 0
  kstage(16384);    // K(1) -> slot 1
  vstage(0);        // V(0) -> slot 0
  __syncthreads();  // vmcnt(0): all landed

  // iter 0: issue K(2),V(1); QK(0); publish P(0) parity 0; counted barrier.
  kstage(32768);    // K(2) -> slot 2
  vstage(16384);    // V(1) -> slot 1
  {
    f32x16 s = do_qk(0);
    do_softpub(s, 0);
  }
  __builtin_amdgcn_sched_barrier(0);
  asm volatile("s_waitcnt vmcnt(4) lgkmcnt(0)\n\ts_barrier" ::: "memory");
  __builtin_amdgcn_sched_barrier(0);

  // steady state t=1..31. kr = t%3 (K read slot), vr = (t-1)%3 (V read slot),
  // write slots = (read+2)%3. prd = ((t-1)&1)*8192.
  int kr = 1, vr = 0, prd = 0;
  for (int it = 1; it < 32; ++it) {
    int kw = (kr == 0) ? 2 : kr - 1;  // (kr+2)%3
    int vw = (vr == 0) ? 2 : vr - 1;
    if (it == 30) kpr -= (size_t)(N_ / 2) * C_;  // K(32) -> wrap (dummy)
    kstage(kw * 16384);
    if (it == 31) vpr -= N_ / 2;                 // V(32) -> wrap (dummy)
    vstage(vw * 16384);
    f32x16 s = do_qk(kr * 16384);
    do_pv(prd, vr * 16384);
    do_softpub(s, prd ^ 8192);
    __builtin_amdgcn_sched_barrier(0);
    asm volatile("s_waitcnt vmcnt(4) lgkmcnt(0)\n\ts_barrier" ::: "memory");
    __builtin_amdgcn_sched_barrier(0);
    prd ^= 8192;
    kr = (kr == 2) ? 0 : kr + 1;
    vr = (vr == 2) ? 0 : vr + 1;
  }
  // drain PV(31): P parity 1 (prd == 8192 now), V(31) slot 31%3 = 2.
  do_pv(prd, 32768);

  // ---- write l partials; stage O^T (bf16) into M for the out-proj GEMM
  float* ml = Ml + ((size_t)(jh * 2 + hh) * B_ + b) * N_;
  if (lane < 32) ml[i0 + mh * 32 + l32] = l_i;
  __syncthreads();  // full drain: PV reads + last dummy loads land before reuse

  u16* M = (u16*)raw;  // [128][264]
#pragma unroll
  for (int ct = 0; ct < 4; ++ct)
#pragma unroll
    for (int g = 0; g < 4; ++g) {
      u16x4 pkv = {f2bf_fast(o[ct][4 * g + 0]), f2bf_fast(o[ct][4 * g + 1]),
                   f2bf_fast(o[ct][4 * g + 2]), f2bf_fast(o[ct][4 * g + 3])};
      *(u16x4*)&M[(mh * 32 + l32) * 264 + hh * 128 + ct * 32 + 8 * g +
                  4 * half] = pkv;
    }
  __syncthreads();

  // ---- fused out-proj: U_h[oc][px] = sum_c Wob[oc][c] * M[px][c]; bf16 out.
  {
    BF8 wf[16];
    const u16* wrow = Wob + ((size_t)w * 16 * 64 + lane) * 8;
#pragma unroll
    for (int ks = 0; ks < 16; ++ks)
      wf[ks].u = *(const u16x8*)(wrow + (size_t)ks * 64 * 8);
    u16* up = U + (((size_t)jh * B_ + b) * C_ + w * 32) * (size_t)N_ + i0;
#pragma unroll
    for (int pxt = 0; pxt < 4; ++pxt) {
      BF8 xf[16];
#pragma unroll
      for (int ks = 0; ks < 16; ++ks)
        xf[ks].u =
            *(const u16x8*)&M[(pxt * 32 + l32) * 264 + ks * 16 + half * 8];
      f32x16 a;
#pragma unroll
      for (int r = 0; r < 16; ++r) a[r] = 0.f;
#pragma unroll
      for (int ks = 0; ks < 16; ++ks) a = mfma32(wf[ks].b, xf[ks].b, a);
#pragma unroll
      for (int r = 0; r < 16; ++r)
        up[(size_t)ROWMAP(r, half) * N_ + pxt * 32 + l32] = f2bf_fast(a[r]);
    }
  }
}

extern "C" void kernel_launch(void* const* d_in, const int* in_sizes, int n_in,
                              void* d_out, int out_size, void* d_ws,
                              size_t ws_size, hipStream_t stream) {
  (void)in_sizes; (void)n_in; (void)out_size; (void)ws_size;
  const float* x = (const float*)d_in[0];
  const float* w_qkv = (const float*)d_in[1];
  const float* b_qkv = (const float*)d_in[2];
  const float* w_out = (const float*)d_in[3];
  const float* b_out = (const float*)d_in[4];
  float* outp = (float*)d_out;

  const size_t TENS = (size_t)B_ * N_ * C_;  // 4M elems
  u8* Qt = (u8*)d_ws;           // [B][N][C] fp8 (scaled)      4 MB
  u8* Kt = Qt + TENS;           // [B][N][C] fp8 (scaled)      4 MB
  u8* Vn = Kt + TENS;           // [B][C][N] fp8               4 MB
  u16* U = (u16*)(Vn + TENS);                   // [2][B][C][N] bf16 16 MB
  float* Ml = (float*)(U + 2 * TENS);           // [4][B][N]  256 KB
  u16* Wqb = (u16*)(Ml + 4 * (size_t)B_ * N_);  // [3C][C]    384 KB
  u16* Wob = Wqb + 3 * C_ * C_;                 // [C][C]     128 KB

  k_prep<<<dim3(128), 256, 0, stream>>>(w_qkv, w_out, Wqb, Wob);
  k_qkv<<<dim3(64, 2, 4), 256, 0, stream>>>(Wqb, b_qkv, x, Qt, Kt, Vn);
  k_attn<<<dim3(256), 512, 0, stream>>>(Qt, Kt, Vn, Wob, U, Ml);
  k_out<<<dim3(2048), 256, 0, stream>>>(b_out, x, outp, U, Ml);
}